// Round 3
// baseline (1032.252 us; speedup 1.0000x reference)
//
#include <hip/hip_runtime.h>
#include <hip/hip_bf16.h>

// Problem constants
#define NTOK 4096      // B*T
#define DDIM 1024
#define GG 4
#define EE 4
#define FF 4096
#define NEXP 16        // G*E
#define MAXTILES 80    // max sum of ceil(cnt/128) over experts = 64+15, padded
#define OUT_ELEMS 4194304        // N*D
#define GL_OFF 4194304           // group_logits offset in d_out (floats)
#define ENT_OFF 4210688          // entropy offset

typedef float f32x4 __attribute__((ext_vector_type(4)));
typedef short short8 __attribute__((ext_vector_type(8)));

__device__ inline unsigned short f2bf(float f) {
  unsigned int u = __float_as_uint(f);
  unsigned int rounding = 0x7FFFu + ((u >> 16) & 1u);
  return (unsigned short)((u + rounding) >> 16);
}
__device__ inline unsigned int pack2(float f0, float f1) {
  return (unsigned int)f2bf(f0) | ((unsigned int)f2bf(f1) << 16);
}
// round-half-up pack (cheaper). Max err identical (0.5 ulp).
__device__ inline unsigned int pack2rn(float f0, float f1) {
  unsigned int u0 = __float_as_uint(f0), u1 = __float_as_uint(f1);
  return ((u0 + 0x8000u) >> 16) | ((u1 + 0x8000u) & 0xFFFF0000u);
}

// async global->LDS, 16B per lane. LDS dest: wave-uniform base + lane*16.
__device__ __forceinline__ void gload_lds16(const void* g, void* l) {
  __builtin_amdgcn_global_load_lds(
      (const __attribute__((address_space(1))) unsigned int*)g,
      (__attribute__((address_space(3))) unsigned int*)l, 16, 0, 0);
}

// ---------------- routing (+ x->bf16 pack, block-reduced entropy) ----------
__global__ __launch_bounds__(256) void routing_kernel(
    const float* __restrict__ x, const float* __restrict__ Wg,
    const float* __restrict__ We, float* __restrict__ out,
    int* __restrict__ cnt, int* __restrict__ tokL, int* __restrict__ hrwL,
    float* __restrict__ wslot, unsigned short* __restrict__ xb,
    float* __restrict__ entPart) {
  int wave = threadIdx.x >> 6, lane = threadIdx.x & 63;
  int token = blockIdx.x * 4 + wave;
  const float4* xr = reinterpret_cast<const float4*>(x + (size_t)token * DDIM);
  float4 xv[4];
#pragma unroll
  for (int c = 0; c < 4; c++) xv[c] = xr[c * 64 + lane];

  // fold x -> bf16 (replaces the old cvt_kernel; same RNE rounding)
  {
    uint2* xbr = reinterpret_cast<uint2*>(xb + (size_t)token * DDIM);
#pragma unroll
    for (int c = 0; c < 4; c++) {
      uint2 pv;
      pv.x = pack2(xv[c].x, xv[c].y);
      pv.y = pack2(xv[c].z, xv[c].w);
      xbr[c * 64 + lane] = pv;
    }
  }

  auto dotrow = [&](const float* w) -> float {
    const float4* w4 = reinterpret_cast<const float4*>(w);
    float s = 0.f;
#pragma unroll
    for (int c = 0; c < 4; c++) {
      float4 wv = w4[c * 64 + lane];
      s += xv[c].x * wv.x + xv[c].y * wv.y + xv[c].z * wv.z + xv[c].w * wv.w;
    }
#pragma unroll
    for (int off = 32; off; off >>= 1) s += __shfl_xor(s, off, 64);
    return s;
  };

  float gl[GG];
#pragma unroll
  for (int g = 0; g < GG; g++) gl[g] = dotrow(Wg + g * DDIM);

  // top-2 groups (ties -> lower index, strict >)
  int g0 = 0;
  for (int g = 1; g < GG; g++) if (gl[g] > gl[g0]) g0 = g;
  int g1 = -1;
  for (int g = 0; g < GG; g++) { if (g == g0) continue; if (g1 < 0 || gl[g] > gl[g1]) g1 = g; }
  float e1 = __expf(gl[g1] - gl[g0]);
  float inv = 1.f / (1.f + e1);
  float w0 = inv, w1 = e1 * inv;

  // top-1 expert within each selected group
  int gsel[2] = {g0, g1};
  float wsel[2] = {w0, w1};
  int esel[2];
#pragma unroll
  for (int r = 0; r < 2; r++) {
    float el[EE];
#pragma unroll
    for (int e = 0; e < EE; e++) el[e] = dotrow(We + ((size_t)gsel[r] * EE + e) * DDIM);
    int best = 0;
    for (int e = 1; e < EE; e++) if (el[e] > el[best]) best = e;
    esel[r] = best;
  }

  // entropy of softmax over all 4 group logits
  float m = gl[0];
  for (int g = 1; g < GG; g++) m = fmaxf(m, gl[g]);
  float se = 0.f;
  for (int g = 0; g < GG; g++) se += __expf(gl[g] - m);
  float lse = __logf(se);
  float ent = 0.f;
  for (int g = 0; g < GG; g++) {
    float lp = gl[g] - m - lse;
    ent -= __expf(lp) * lp;
  }

  __shared__ float entS[4];
  if (lane == 0) {
    entS[wave] = ent;
    for (int g = 0; g < GG; g++) out[GL_OFF + token * GG + g] = gl[g];
    for (int r = 0; r < 2; r++) {
      int ge = gsel[r] * EE + esel[r];
      int pos = atomicAdd(cnt + ge, 1);
      tokL[ge * NTOK + pos] = token;
      hrwL[ge * NTOK + pos] = r * NTOK + token;
      wslot[r * NTOK + token] = wsel[r];
    }
  }
  __syncthreads();
  if (threadIdx.x == 0)
    entPart[blockIdx.x] = entS[0] + entS[1] + entS[2] + entS[3];
}

// ---------------- entropy finalize: sum 1024 per-block partials ------------
__global__ void ent_finalize(const float* __restrict__ entPart,
                             float* __restrict__ out) {
  int t = threadIdx.x;
  float s = 0.f;
  for (int i = t; i < 1024; i += 256) s += entPart[i];
#pragma unroll
  for (int off = 32; off; off >>= 1) s += __shfl_xor(s, off, 64);
  __shared__ float ws4[4];
  if ((t & 63) == 0) ws4[t >> 6] = s;
  __syncthreads();
  if (t == 0) out[ENT_OFF] = (ws4[0] + ws4[1] + ws4[2] + ws4[3]) * (1.0f / NTOK);
}

// ================= expert GEMM (2-phase, BK=64, 4 waves, 64x64/wave) =======
// Tile 128(M) x 128(N) x 64(K). 256 threads = 4 waves (2x2), wave tile 64x64
// -> acc[4][4] 16x16 frags, 32 MFMA per wave per K-tile, 16 ds_read_b128
// (2 MFMA per LDS read, was 1.33). blockIdx.y -> (ge, mt) via on-the-fly
// prefix over cnt (compact grid, no mt-sweep waste). Loop order: issue B
// global loads FIRST, then A gload_lds, then MFMAs, then pack+ds_write B ->
// both A and B get a full-iteration latency window.
template <int KDIM, bool UP>
__global__ __launch_bounds__(256, 2) void moe_gemm(
    const unsigned short* __restrict__ A, const float* __restrict__ W,
    const int* __restrict__ cnt, const int* __restrict__ tokL,
    const int* __restrict__ hrwL, unsigned short* __restrict__ Hout,
    float* __restrict__ Yout) {
  constexpr int NT = KDIM / 64;
  constexpr int NROWS = UP ? FF : DDIM;
  // map blockIdx.y -> (ge, mt)
  int ge = -1, mt = 0;
  {
    int y = blockIdx.y, a = 0;
    for (int g = 0; g < NEXP; g++) {
      int ntl = (cnt[g] + 127) >> 7;
      if (y < a + ntl) { ge = g; mt = y - a; break; }
      a += ntl;
    }
  }
  if (ge < 0) return;
  int count = cnt[ge];
  int n0 = blockIdx.x * 128;

  __shared__ alignas(16) unsigned short As[2][128 * 64];
  __shared__ alignas(16) unsigned short Bs[2][128 * 64];
  __shared__ int srcS[128];
  __shared__ int dstS[128];

  int t = threadIdx.x;
  int w = t >> 6, lane = t & 63;
  if (t < 128) {
    int i = mt * 128 + t;
    bool valid = i < count;
    int hrw = valid ? hrwL[ge * NTOK + i] : -1;
    dstS[t] = hrw;
    if (UP) srcS[t] = valid ? tokL[ge * NTOK + i] : 0;
    else    srcS[t] = hrw < 0 ? 0 : hrw;
  }
  __syncthreads();

  // A staging: wave w stages rows w*32 .. w*32+31 (4 gload calls x 8 rows).
  // Source chunk pre-swizzled (lane&7)^(row&7); LDS dest linear (rule #21).
  int cA = (lane & 7) ^ (lane >> 3);
  const unsigned short* gA[4];
#pragma unroll
  for (int c = 0; c < 4; c++)
    gA[c] = A + (size_t)srcS[w * 32 + c * 8 + (lane >> 3)] * KDIM + cA * 8;

  // B staging: thread covers rows rB+{0,32,64,96}, chunk cB (8 f32 -> 8 bf16)
  int rB = t >> 3, cB = t & 7;
  const float* gB = W + ((size_t)ge * NROWS + n0 + rB) * KDIM + cB * 8;
  int pB = (cB ^ (rB & 7)) * 8;   // phys chunk offset in shorts

  int wr = w >> 1, wc = w & 1;
  int m0 = wr * 64, nw = wc * 64;
  int rl = lane & 15, kq = lane >> 4;
  int xr = rl & 7;

  f32x4 acc[4][4] = {};
  int cur = 0;

  // prologue: stage tile 0 into buffer 0
  {
    float4 q[8];
#pragma unroll
    for (int qq = 0; qq < 4; qq++) {
      q[qq * 2]     = *reinterpret_cast<const float4*>(gB + (size_t)(qq * 32) * KDIM);
      q[qq * 2 + 1] = *reinterpret_cast<const float4*>(gB + (size_t)(qq * 32) * KDIM + 4);
    }
#pragma unroll
    for (int c = 0; c < 4; c++)
      gload_lds16(gA[c], &As[0][(w * 32 + c * 8) * 64]);
#pragma unroll
    for (int qq = 0; qq < 4; qq++) {
      uint4 v;
      v.x = pack2rn(q[qq * 2].x, q[qq * 2].y);
      v.y = pack2rn(q[qq * 2].z, q[qq * 2].w);
      v.z = pack2rn(q[qq * 2 + 1].x, q[qq * 2 + 1].y);
      v.w = pack2rn(q[qq * 2 + 1].z, q[qq * 2 + 1].w);
      *reinterpret_cast<uint4*>(&Bs[0][(rB + qq * 32) * 64 + pB]) = v;
    }
  }
  __syncthreads();

  for (int it = 0; it < NT; ++it) {
    int kb = (it + 1) * 64;
    bool pre = (it + 1) < NT;
    float4 q[8];
    if (pre) {
      // issue next-tile B loads first, then A DMAs: full-iter latency window
#pragma unroll
      for (int qq = 0; qq < 4; qq++) {
        q[qq * 2]     = *reinterpret_cast<const float4*>(gB + (size_t)(qq * 32) * KDIM + kb);
        q[qq * 2 + 1] = *reinterpret_cast<const float4*>(gB + (size_t)(qq * 32) * KDIM + kb + 4);
      }
#pragma unroll
      for (int c = 0; c < 4; c++)
        gload_lds16(gA[c] + kb, &As[cur ^ 1][(w * 32 + c * 8) * 64]);
    }
    // compute current tile: 32 MFMA, 16 ds_read_b128 per wave
    const unsigned short* Ab = As[cur];
    const unsigned short* Bb = Bs[cur];
#pragma unroll
    for (int kk = 0; kk < 2; kk++) {
      int cph = ((kk * 4 + kq) ^ xr) * 8;
      short8 af[4];
#pragma unroll
      for (int i = 0; i < 4; i++)
        af[i] = *reinterpret_cast<const short8*>(&Ab[(m0 + i * 16 + rl) * 64 + cph]);
#pragma unroll
      for (int j = 0; j < 4; j++) {
        short8 bf = *reinterpret_cast<const short8*>(&Bb[(nw + j * 16 + rl) * 64 + cph]);
#pragma unroll
        for (int i = 0; i < 4; i++)
          acc[i][j] = __builtin_amdgcn_mfma_f32_16x16x32_bf16(af[i], bf, acc[i][j], 0, 0, 0);
      }
    }
    if (pre) {
      // pack+write AFTER the MFMAs: B regs had the whole compute to arrive
#pragma unroll
      for (int qq = 0; qq < 4; qq++) {
        uint4 v;
        v.x = pack2rn(q[qq * 2].x, q[qq * 2].y);
        v.y = pack2rn(q[qq * 2].z, q[qq * 2].w);
        v.z = pack2rn(q[qq * 2 + 1].x, q[qq * 2 + 1].y);
        v.w = pack2rn(q[qq * 2 + 1].z, q[qq * 2 + 1].w);
        *reinterpret_cast<uint4*>(&Bs[cur ^ 1][(rB + qq * 32) * 64 + pB]) = v;
      }
    }
    __syncthreads();   // drains A DMAs (vmcnt) + B ds_writes once per K-tile
    cur ^= 1;
  }

  // epilogue
  int re = kq * 4;
#pragma unroll
  for (int i = 0; i < 4; i++) {
#pragma unroll
    for (int e = 0; e < 4; e++) {
      int hr = dstS[m0 + i * 16 + re + e];
      if (hr >= 0) {
        if constexpr (UP) {
#pragma unroll
          for (int j = 0; j < 4; j++) {
            float v = acc[i][j][e];
            float gel = 0.5f * v * (1.0f + erff(v * 0.70710678118654752f));
            Hout[(size_t)hr * FF + n0 + nw + j * 16 + rl] = f2bf(gel);
          }
        } else {
#pragma unroll
          for (int j = 0; j < 4; j++)
            Yout[(size_t)hr * DDIM + n0 + nw + j * 16 + rl] = acc[i][j][e];
        }
      }
    }
  }
}

// ---------------- combine: out = w0*Y0 + w1*Y1 ----------------
__global__ void combine_kernel(const float* __restrict__ Y,
                               const float* __restrict__ wslot,
                               float* __restrict__ out) {
  int idx = blockIdx.x * 256 + threadIdx.x;    // one float4 per thread
  int token = idx >> 8;                        // 256 float4 per row
  float w0 = wslot[token], w1 = wslot[NTOK + token];
  float4 a = reinterpret_cast<const float4*>(Y)[idx];
  float4 b = reinterpret_cast<const float4*>(Y + (size_t)NTOK * DDIM)[idx];
  float4 o;
  o.x = w0 * a.x + w1 * b.x;
  o.y = w0 * a.y + w1 * b.y;
  o.z = w0 * a.z + w1 * b.z;
  o.w = w0 * a.w + w1 * b.w;
  reinterpret_cast<float4*>(out)[idx] = o;
}

extern "C" void kernel_launch(void* const* d_in, const int* in_sizes, int n_in,
                              void* d_out, int out_size, void* d_ws, size_t ws_size,
                              hipStream_t stream) {
  const float* x  = (const float*)d_in[0];
  const float* Wg = (const float*)d_in[1];
  const float* We = (const float*)d_in[2];
  const float* W1 = (const float*)d_in[3];
  const float* W2 = (const float*)d_in[4];
  float* out = (float*)d_out;
  char* ws = (char*)d_ws;

  // workspace layout
  int* cnt = (int*)(ws);                               // 64 B (zeroed)
  int* tokL = (int*)(ws + 1024);                       // 16*4096*4
  int* hrwL = (int*)(ws + 1024 + 262144);              // 16*4096*4
  float* wslot = (float*)(ws + 1024 + 524288);         // 2*4096*4
  float* entPart = (float*)(ws + 1024 + 524288 + 32768); // 1024*4
  unsigned short* xb = (unsigned short*)(ws + (1 << 20));            // 8 MB
  unsigned short* H  = (unsigned short*)(ws + (1 << 20) + 8388608);  // 67 MB
  float* Y = (float*)(ws + (1 << 20) + 8388608 + 67108864);          // 33.5 MB

  hipMemsetAsync(d_out, 0, (size_t)out_size * sizeof(float), stream);
  hipMemsetAsync(ws, 0, 1024, stream);

  routing_kernel<<<1024, 256, 0, stream>>>(x, Wg, We, out, cnt, tokL, hrwL,
                                           wslot, xb, entPart);
  moe_gemm<DDIM, true><<<dim3(FF / 128, MAXTILES), 256, 0, stream>>>(
      xb, W1, cnt, tokL, hrwL, H, nullptr);
  moe_gemm<FF, false><<<dim3(DDIM / 128, MAXTILES), 256, 0, stream>>>(
      H, W2, cnt, tokL, hrwL, nullptr, Y);
  combine_kernel<<<4096, 256, 0, stream>>>(Y, wslot, out);
  ent_finalize<<<1, 256, 0, stream>>>(entPart, out);
}

// Round 4
// 975.006 us; speedup vs baseline: 1.0587x; 1.0587x over previous
//
#include <hip/hip_runtime.h>
#include <hip/hip_bf16.h>

// Problem constants
#define NTOK 4096      // B*T
#define DDIM 1024
#define GG 4
#define EE 4
#define FF 4096
#define NEXP 16        // G*E
#define MAXTILES 80    // max sum of ceil(cnt/128) over experts = 64+15, padded
#define OUT_ELEMS 4194304        // N*D
#define GL_OFF 4194304           // group_logits offset in d_out (floats)
#define ENT_OFF 4210688          // entropy offset

typedef float f32x4 __attribute__((ext_vector_type(4)));
typedef short short8 __attribute__((ext_vector_type(8)));

__device__ inline unsigned short f2bf(float f) {
  unsigned int u = __float_as_uint(f);
  unsigned int rounding = 0x7FFFu + ((u >> 16) & 1u);
  return (unsigned short)((u + rounding) >> 16);
}
__device__ inline unsigned int pack2(float f0, float f1) {
  return (unsigned int)f2bf(f0) | ((unsigned int)f2bf(f1) << 16);
}
// round-half-up pack (cheaper). Max err identical (0.5 ulp).
__device__ inline unsigned int pack2rn(float f0, float f1) {
  unsigned int u0 = __float_as_uint(f0), u1 = __float_as_uint(f1);
  return ((u0 + 0x8000u) >> 16) | ((u1 + 0x8000u) & 0xFFFF0000u);
}

// async global->LDS, 16B per lane. LDS dest: wave-uniform base + lane*16.
__device__ __forceinline__ void gload_lds16(const void* g, void* l) {
  __builtin_amdgcn_global_load_lds(
      (const __attribute__((address_space(1))) unsigned int*)g,
      (__attribute__((address_space(3))) unsigned int*)l, 16, 0, 0);
}

// ---------------- routing (+ x->bf16 pack, block-reduced entropy) ----------
__global__ __launch_bounds__(256) void routing_kernel(
    const float* __restrict__ x, const float* __restrict__ Wg,
    const float* __restrict__ We, float* __restrict__ out,
    int* __restrict__ cnt, int* __restrict__ tokL, int* __restrict__ hrwL,
    float* __restrict__ wslot, unsigned short* __restrict__ xb,
    float* __restrict__ entPart) {
  int wave = threadIdx.x >> 6, lane = threadIdx.x & 63;
  int token = blockIdx.x * 4 + wave;
  const float4* xr = reinterpret_cast<const float4*>(x + (size_t)token * DDIM);
  float4 xv[4];
#pragma unroll
  for (int c = 0; c < 4; c++) xv[c] = xr[c * 64 + lane];

  // fold x -> bf16 (same RNE rounding as before)
  {
    uint2* xbr = reinterpret_cast<uint2*>(xb + (size_t)token * DDIM);
#pragma unroll
    for (int c = 0; c < 4; c++) {
      uint2 pv;
      pv.x = pack2(xv[c].x, xv[c].y);
      pv.y = pack2(xv[c].z, xv[c].w);
      xbr[c * 64 + lane] = pv;
    }
  }

  auto dotrow = [&](const float* w) -> float {
    const float4* w4 = reinterpret_cast<const float4*>(w);
    float s = 0.f;
#pragma unroll
    for (int c = 0; c < 4; c++) {
      float4 wv = w4[c * 64 + lane];
      s += xv[c].x * wv.x + xv[c].y * wv.y + xv[c].z * wv.z + xv[c].w * wv.w;
    }
#pragma unroll
    for (int off = 32; off; off >>= 1) s += __shfl_xor(s, off, 64);
    return s;
  };

  float gl[GG];
#pragma unroll
  for (int g = 0; g < GG; g++) gl[g] = dotrow(Wg + g * DDIM);

  // top-2 groups (ties -> lower index, strict >)
  int g0 = 0;
  for (int g = 1; g < GG; g++) if (gl[g] > gl[g0]) g0 = g;
  int g1 = -1;
  for (int g = 0; g < GG; g++) { if (g == g0) continue; if (g1 < 0 || gl[g] > gl[g1]) g1 = g; }
  float e1 = __expf(gl[g1] - gl[g0]);
  float inv = 1.f / (1.f + e1);
  float w0 = inv, w1 = e1 * inv;

  // top-1 expert within each selected group
  int gsel[2] = {g0, g1};
  float wsel[2] = {w0, w1};
  int esel[2];
#pragma unroll
  for (int r = 0; r < 2; r++) {
    float el[EE];
#pragma unroll
    for (int e = 0; e < EE; e++) el[e] = dotrow(We + ((size_t)gsel[r] * EE + e) * DDIM);
    int best = 0;
    for (int e = 1; e < EE; e++) if (el[e] > el[best]) best = e;
    esel[r] = best;
  }

  // entropy of softmax over all 4 group logits
  float m = gl[0];
  for (int g = 1; g < GG; g++) m = fmaxf(m, gl[g]);
  float se = 0.f;
  for (int g = 0; g < GG; g++) se += __expf(gl[g] - m);
  float lse = __logf(se);
  float ent = 0.f;
  for (int g = 0; g < GG; g++) {
    float lp = gl[g] - m - lse;
    ent -= __expf(lp) * lp;
  }

  __shared__ float entS[4];
  if (lane == 0) {
    entS[wave] = ent;
    for (int g = 0; g < GG; g++) out[GL_OFF + token * GG + g] = gl[g];
    for (int r = 0; r < 2; r++) {
      int ge = gsel[r] * EE + esel[r];
      int pos = atomicAdd(cnt + ge, 1);
      tokL[ge * NTOK + pos] = token;
      hrwL[ge * NTOK + pos] = r * NTOK + token;
      wslot[r * NTOK + token] = wsel[r];
    }
  }
  __syncthreads();
  if (threadIdx.x == 0)
    entPart[blockIdx.x] = entS[0] + entS[1] + entS[2] + entS[3];
}

// ---------------- entropy finalize: sum 1024 per-block partials ------------
__global__ void ent_finalize(const float* __restrict__ entPart,
                             float* __restrict__ out) {
  int t = threadIdx.x;
  float s = 0.f;
  for (int i = t; i < 1024; i += 256) s += entPart[i];
#pragma unroll
  for (int off = 32; off; off >>= 1) s += __shfl_xor(s, off, 64);
  __shared__ float ws4[4];
  if ((t & 63) == 0) ws4[t >> 6] = s;
  __syncthreads();
  if (t == 0) out[ENT_OFF] = (ws4[0] + ws4[1] + ws4[2] + ws4[3]) * (1.0f / NTOK);
}

// ================= expert GEMM: 2-deep pipelined, counted vmcnt ============
// Tile 128x128x64. 512 threads = 8 waves (4x2), wave tile 32x64, 16 MFMA/
// wave/K-tile (round-2 shape, which measured best). Pipeline:
//   iter t: issue A(t+1) gload_lds -> As[(t+1)&1]   (pinned FIRST)
//           issue B(t+2) global->regs set[t&1]      (pinned AFTER A)
//           compute t from As[t&1], Bs[t&1]
//           pack B(t+1) regs -> Bs[(t+1)&1]         (reg-dep waits, ~2 iters old)
//           s_waitcnt vmcnt(4) lgkmcnt(0); s_barrier  (A drained; B(t+2) stays
//           in flight ACROSS the barrier -- the T4 counted-vmcnt lever)
// Loop unrolled x2 so reg sets qa/qb are statically indexed (rule #20).
template <int KDIM, bool UP>
__global__ __launch_bounds__(512, 4) void moe_gemm(
    const unsigned short* __restrict__ A, const float* __restrict__ W,
    const int* __restrict__ cnt, const int* __restrict__ tokL,
    const int* __restrict__ hrwL, unsigned short* __restrict__ Hout,
    float* __restrict__ Yout) {
  constexpr int NT = KDIM / 64;   // 16 (up) or 64 (down), both even
  constexpr int NROWS = UP ? FF : DDIM;
  // map blockIdx.y -> (ge, mt) (compact grid)
  int ge = -1, mt = 0;
  {
    int y = blockIdx.y, a = 0;
    for (int g = 0; g < NEXP; g++) {
      int ntl = (cnt[g] + 127) >> 7;
      if (y < a + ntl) { ge = g; mt = y - a; break; }
      a += ntl;
    }
  }
  if (ge < 0) return;
  int count = cnt[ge];
  int n0 = blockIdx.x * 128;

  __shared__ alignas(16) unsigned short As[2][128 * 64];
  __shared__ alignas(16) unsigned short Bs[2][128 * 64];
  __shared__ int srcS[128];
  __shared__ int dstS[128];

  int t = threadIdx.x;
  int w = t >> 6, lane = t & 63;
  if (t < 128) {
    int i = mt * 128 + t;
    bool valid = i < count;
    int hrw = valid ? hrwL[ge * NTOK + i] : -1;
    dstS[t] = hrw;
    if (UP) srcS[t] = valid ? tokL[ge * NTOK + i] : 0;
    else    srcS[t] = hrw < 0 ? 0 : hrw;
  }
  __syncthreads();

  // A staging: wave w stages rows w*16..w*16+15 (2 gload calls x 8 rows).
  // Source chunk pre-swizzled (lane&7)^(row&7); LDS dest linear (rule #21).
  int rA = w * 16 + (lane >> 3);
  int cA = (lane & 7) ^ (lane >> 3);
  const unsigned short* gA0 = A + (size_t)srcS[rA] * KDIM + cA * 8;
  const unsigned short* gA1 = A + (size_t)srcS[rA + 8] * KDIM + cA * 8;

  // B staging: thread covers rows rB and rB+64, chunk cB (8 f32 each)
  int rB = t >> 3, cB = t & 7;
  const float* gB0 = W + ((size_t)ge * NROWS + n0 + rB) * KDIM + cB * 8;
  const float* gB1 = W + ((size_t)ge * NROWS + n0 + 64 + rB) * KDIM + cB * 8;
  int pB = (cB ^ (rB & 7)) * 8;   // phys chunk offset in shorts

  int wr = w >> 1, wc = w & 1;
  int m0 = wr * 32, nw = wc * 64;
  int rl = lane & 15, kq = lane >> 4;
  int xr = rl & 7;

  f32x4 acc[2][4] = {};
  float4 qa[4], qb[4];

  auto loadB = [&](float4* q, int kb) {
    q[0] = *reinterpret_cast<const float4*>(gB0 + kb);
    q[1] = *reinterpret_cast<const float4*>(gB0 + kb + 4);
    q[2] = *reinterpret_cast<const float4*>(gB1 + kb);
    q[3] = *reinterpret_cast<const float4*>(gB1 + kb + 4);
  };
  auto packB = [&](const float4* q, unsigned short* buf) {
    uint4 v0, v1;
    v0.x = pack2rn(q[0].x, q[0].y); v0.y = pack2rn(q[0].z, q[0].w);
    v0.z = pack2rn(q[1].x, q[1].y); v0.w = pack2rn(q[1].z, q[1].w);
    v1.x = pack2rn(q[2].x, q[2].y); v1.y = pack2rn(q[2].z, q[2].w);
    v1.z = pack2rn(q[3].x, q[3].y); v1.w = pack2rn(q[3].z, q[3].w);
    *reinterpret_cast<uint4*>(&buf[rB * 64 + pB]) = v0;
    *reinterpret_cast<uint4*>(&buf[(rB + 64) * 64 + pB]) = v1;
  };
  auto stageA = [&](int buf, int kb) {
    gload_lds16(gA0 + kb, &As[buf][(w * 16) * 64]);
    gload_lds16(gA1 + kb, &As[buf][(w * 16 + 8) * 64]);
  };
  auto compute = [&](const unsigned short* Ab, const unsigned short* Bb) {
#pragma unroll
    for (int kk = 0; kk < 2; kk++) {
      int cph = ((kk * 4 + kq) ^ xr) * 8;
      short8 af0 = *reinterpret_cast<const short8*>(&Ab[(m0 + rl) * 64 + cph]);
      short8 af1 = *reinterpret_cast<const short8*>(&Ab[(m0 + 16 + rl) * 64 + cph]);
#pragma unroll
      for (int j = 0; j < 4; j++) {
        short8 bf = *reinterpret_cast<const short8*>(&Bb[(nw + j * 16 + rl) * 64 + cph]);
        acc[0][j] = __builtin_amdgcn_mfma_f32_16x16x32_bf16(af0, bf, acc[0][j], 0, 0, 0);
        acc[1][j] = __builtin_amdgcn_mfma_f32_16x16x32_bf16(af1, bf, acc[1][j], 0, 0, 0);
      }
    }
  };

  // Prologue: B(0)->qa, A(0) (issue order pinned: A before B(1)), B(1)->qb.
  loadB(qa, 0);
  stageA(0, 0);
  __builtin_amdgcn_sched_barrier(0);   // pin: A issued before qb loads
  loadB(qb, 64);
  packB(qa, Bs[0]);                    // reg-dep drains B(0)
  asm volatile("s_waitcnt vmcnt(4) lgkmcnt(0)" ::: "memory");  // drain A(0); qb flies
  __builtin_amdgcn_s_barrier();
  __builtin_amdgcn_sched_barrier(0);

  for (int it = 0; it < NT; it += 2) {
    // ---- even body: t=it, compute buf0; pack qb->Bs[1]; load qa=B(t+2) ----
    {
      int tt = it;
      stageA(1, (tt + 1) * 64);                  // A(t+1), always valid (tt<=NT-2)
      __builtin_amdgcn_sched_barrier(0);         // pin A before B issue
      if (tt + 2 < NT) loadB(qa, (tt + 2) * 64);
      compute(As[0], Bs[0]);
      packB(qb, Bs[1]);                          // B(t+1), reg-dep (2 iters old)
      if (tt + 2 < NT)
        asm volatile("s_waitcnt vmcnt(4) lgkmcnt(0)" ::: "memory");
      else
        asm volatile("s_waitcnt vmcnt(0) lgkmcnt(0)" ::: "memory");
      __builtin_amdgcn_s_barrier();
      __builtin_amdgcn_sched_barrier(0);
    }
    // ---- odd body: t=it+1, compute buf1; pack qa->Bs[0]; load qb=B(t+2) ---
    {
      int tt = it + 1;
      if (tt + 1 < NT) stageA(0, (tt + 1) * 64);
      __builtin_amdgcn_sched_barrier(0);
      if (tt + 2 < NT) loadB(qb, (tt + 2) * 64);
      compute(As[1], Bs[1]);
      if (tt + 1 < NT) packB(qa, Bs[0]);
      if (tt + 2 < NT)
        asm volatile("s_waitcnt vmcnt(4) lgkmcnt(0)" ::: "memory");
      else
        asm volatile("s_waitcnt vmcnt(0) lgkmcnt(0)" ::: "memory");
      __builtin_amdgcn_s_barrier();
      __builtin_amdgcn_sched_barrier(0);
    }
  }

  // epilogue
  int re = kq * 4;
#pragma unroll
  for (int i = 0; i < 2; i++) {
#pragma unroll
    for (int e = 0; e < 4; e++) {
      int hr = dstS[m0 + i * 16 + re + e];
      if (hr >= 0) {
        if constexpr (UP) {
#pragma unroll
          for (int j = 0; j < 4; j++) {
            float v = acc[i][j][e];
            float gel = 0.5f * v * (1.0f + erff(v * 0.70710678118654752f));
            Hout[(size_t)hr * FF + n0 + nw + j * 16 + rl] = f2bf(gel);
          }
        } else {
#pragma unroll
          for (int j = 0; j < 4; j++)
            Yout[(size_t)hr * DDIM + n0 + nw + j * 16 + rl] = acc[i][j][e];
        }
      }
    }
  }
}

// ---------------- combine: out = w0*Y0 + w1*Y1 ----------------
__global__ void combine_kernel(const float* __restrict__ Y,
                               const float* __restrict__ wslot,
                               float* __restrict__ out) {
  int idx = blockIdx.x * 256 + threadIdx.x;    // one float4 per thread
  int token = idx >> 8;                        // 256 float4 per row
  float w0 = wslot[token], w1 = wslot[NTOK + token];
  float4 a = reinterpret_cast<const float4*>(Y)[idx];
  float4 b = reinterpret_cast<const float4*>(Y + (size_t)NTOK * DDIM)[idx];
  float4 o;
  o.x = w0 * a.x + w1 * b.x;
  o.y = w0 * a.y + w1 * b.y;
  o.z = w0 * a.z + w1 * b.z;
  o.w = w0 * a.w + w1 * b.w;
  reinterpret_cast<float4*>(out)[idx] = o;
}

extern "C" void kernel_launch(void* const* d_in, const int* in_sizes, int n_in,
                              void* d_out, int out_size, void* d_ws, size_t ws_size,
                              hipStream_t stream) {
  const float* x  = (const float*)d_in[0];
  const float* Wg = (const float*)d_in[1];
  const float* We = (const float*)d_in[2];
  const float* W1 = (const float*)d_in[3];
  const float* W2 = (const float*)d_in[4];
  float* out = (float*)d_out;
  char* ws = (char*)d_ws;

  // workspace layout
  int* cnt = (int*)(ws);                               // 64 B (zeroed)
  int* tokL = (int*)(ws + 1024);                       // 16*4096*4
  int* hrwL = (int*)(ws + 1024 + 262144);              // 16*4096*4
  float* wslot = (float*)(ws + 1024 + 524288);         // 2*4096*4
  float* entPart = (float*)(ws + 1024 + 524288 + 32768); // 1024*4
  unsigned short* xb = (unsigned short*)(ws + (1 << 20));            // 8 MB
  unsigned short* H  = (unsigned short*)(ws + (1 << 20) + 8388608);  // 67 MB
  float* Y = (float*)(ws + (1 << 20) + 8388608 + 67108864);          // 33.5 MB

  hipMemsetAsync(d_out, 0, (size_t)out_size * sizeof(float), stream);
  hipMemsetAsync(ws, 0, 1024, stream);

  routing_kernel<<<1024, 256, 0, stream>>>(x, Wg, We, out, cnt, tokL, hrwL,
                                           wslot, xb, entPart);
  moe_gemm<DDIM, true><<<dim3(FF / 128, MAXTILES), 512, 0, stream>>>(
      xb, W1, cnt, tokL, hrwL, H, nullptr);
  moe_gemm<FF, false><<<dim3(DDIM / 128, MAXTILES), 512, 0, stream>>>(
      H, W2, cnt, tokL, hrwL, nullptr, Y);
  combine_kernel<<<4096, 256, 0, stream>>>(Y, wslot, out);
  ent_finalize<<<1, 256, 0, stream>>>(entPart, out);
}